// Round 5
// baseline (203.336 us; speedup 1.0000x reference)
//
#include <hip/hip_runtime.h>
#include <math.h>

#define IMG_H 512
#define IMG_W 512
#define IMG_HW (IMG_H * IMG_W)

namespace {

// float32-rounded cos(k*pi/16) values
constexpr float CFv[9] = {
    1.0f,
    0.98078528040323044913f,
    0.92387953251128675613f,
    0.83146961230254523708f,
    0.70710678118654752440f,
    0.55557023301960222474f,
    0.38268343236508977173f,
    0.19509032201612826785f,
    0.0f
};

struct CTab {
    float  cf[8][8];     // C[x][u] = f32(cos((2x+1)u pi/16))
    double cd[8][8];     // promoted to double
    float  aof[8][8];    // ALPHA outer product (f32)
    float  scalef[8][8]; // DCT_SCALE = ALPHA*0.25
};

constexpr CTab make_ctab() {
    CTab t{};
    for (int y = 0; y < 8; y++) {
        for (int v = 0; v < 8; v++) {
            int a = ((2 * y + 1) * v) & 31;
            if (a > 16) a = 32 - a;
            float val = (a <= 8) ? CFv[a] : -CFv[16 - a];
            t.cf[y][v] = val;
            t.cd[y][v] = (double)val;
        }
    }
    constexpr float A0 = 0.70710678118654752440f;
    for (int u = 0; u < 8; u++) {
        for (int v = 0; v < 8; v++) {
            float au = (u == 0) ? A0 : 1.0f;
            float av = (v == 0) ? A0 : 1.0f;
            float ao = au * av;
            t.aof[u][v] = ao;
            t.scalef[u][v] = ao * 0.25f;
        }
    }
    return t;
}

constexpr CTab CT = make_ctab();

// forward 8-pt pass (fp64), even/odd butterfly: s[v] = sum_y a[y]*cd[y][v]
__device__ __forceinline__ void fwd8_d(const double a[8], double s[8]) {
    double e0 = a[0] + a[7], e1 = a[1] + a[6], e2 = a[2] + a[5], e3 = a[3] + a[4];
    double o0 = a[0] - a[7], o1 = a[1] - a[6], o2 = a[2] - a[5], o3 = a[3] - a[4];
    double ee0 = e0 + e3, ee1 = e1 + e2, eo0 = e0 - e3, eo1 = e1 - e2;
    s[0] = ee0 + ee1;
    s[4] = (ee0 - ee1) * CT.cd[0][4];
    s[2] = eo0 * CT.cd[0][2] + eo1 * CT.cd[1][2];
    s[6] = eo0 * CT.cd[0][6] + eo1 * CT.cd[1][6];
    #pragma unroll
    for (int k = 0; k < 4; k++) {
        const int v = 2 * k + 1;
        s[v] = o0 * CT.cd[0][v] + o1 * CT.cd[1][v] + o2 * CT.cd[2][v] + o3 * CT.cd[3][v];
    }
}

// inverse 8-pt pass (fp32), output-symmetry butterfly: m[x] = sum_u d[u]*cf[x][u]
__device__ __forceinline__ void inv8_f(const float d[8], float m[8]) {
    float eea = fmaf(CT.cf[0][4], d[4], d[0]);
    float eeb = fmaf(CT.cf[1][4], d[4], d[0]);
    float u2a = d[2] * CT.cf[0][2] + d[6] * CT.cf[0][6];
    float u2b = d[2] * CT.cf[1][2] + d[6] * CT.cf[1][6];
    float E0 = eea + u2a, E1 = eeb + u2b, E2 = eeb - u2b, E3 = eea - u2a;
    float O0 = d[1] * CT.cf[0][1] + d[3] * CT.cf[0][3] + d[5] * CT.cf[0][5] + d[7] * CT.cf[0][7];
    float O1 = d[1] * CT.cf[1][1] + d[3] * CT.cf[1][3] + d[5] * CT.cf[1][5] + d[7] * CT.cf[1][7];
    float O2 = d[1] * CT.cf[2][1] + d[3] * CT.cf[2][3] + d[5] * CT.cf[2][5] + d[7] * CT.cf[2][7];
    float O3 = d[1] * CT.cf[3][1] + d[3] * CT.cf[3][3] + d[5] * CT.cf[3][5] + d[7] * CT.cf[3][7];
    m[0] = E0 + O0; m[7] = E0 - O0;
    m[1] = E1 + O1; m[6] = E1 - O1;
    m[2] = E2 + O2; m[5] = E2 - O2;
    m[3] = E3 + O3; m[4] = E3 - O3;
}

} // namespace

// ---- LDS layout (bytes) ----------------------------------------------------
// Per-wave region (WAVE_BYTES = 3584), wave w at smem + w*3584; reused for both tiles.
//   lYd  double[16][18] @0     (2304)   Y samples (fp64), row stride 18 dbl
//     f32 overlays of lYd (live only after all fp64 reads retired, same wave):
//     yR  f32 stride 20  @0    ; cbR stride 12 @1280 ; crR stride 12 @1664
//   cbP  double[8][10]  @2304  (640)
//   crP  double[8][10]  @2944  (640)
// Shared quant tables (written by t<128, one initial barrier):
//   qYfs double[8][10] @14336 ; qCfs @14976 ; dsY f32[8][12] @15616 ; dsC @16000
#define WAVE_BYTES 3584
#define OFF_CBP 2304
#define OFF_CRP 2944
#define OFF_CBR 1280
#define OFF_CRR 1664
#define OFF_QYF 14336
#define OFF_QCF 14976
#define OFF_DSY 15616
#define OFF_DSC 16000
#define SMEM_BYTES 16384

__global__ void __launch_bounds__(256, 8) djpeg_kernel(
    const float* __restrict__ img,
    const float* __restrict__ ytab,
    const float* __restrict__ ctab,
    float* __restrict__ out)
{
    __shared__ __align__(16) unsigned char smem[SMEM_BYTES];
    const int t = threadIdx.x;
    const int w = t >> 6, l = t & 63;
    unsigned char* wb = smem + w * WAVE_BYTES;
    double* lYd = (double*)wb;
    double* cbP = (double*)(wb + OFF_CBP);
    double* crP = (double*)(wb + OFF_CRP);
    float*  yR  = (float*)wb;
    float*  cbR = (float*)(wb + OFF_CBR);
    float*  crR = (float*)(wb + OFF_CRR);
    double* qYfs = (double*)(smem + OFF_QYF);
    double* qCfs = (double*)(smem + OFF_QCF);
    float*  dsY  = (float*)(smem + OFF_DSY);
    float*  dsC  = (float*)(smem + OFF_DSC);

    const int bi = blockIdx.z;
    const int X0 = blockIdx.x * 128 + w * 16;  // wave-private tiles at X0 and X0+64
    const int Y0 = blockIdx.y * 16;
    const int q = l & 3, row = l >> 2;         // lane = (row 0..15, col-quad 0..3)

    // issue BOTH tiles' global loads up front (6 KB/wave in flight; tile-B latency
    // hides under tile-A compute)
    const size_t baseA = ((size_t)bi * 3) * IMG_HW + (size_t)(Y0 + row) * IMG_W + X0 + q * 4;
    const size_t baseB = baseA + 64;
    const float4 rfA = *(const float4*)(img + baseA);
    const float4 gfA = *(const float4*)(img + baseA + IMG_HW);
    const float4 bfA = *(const float4*)(img + baseA + 2 * IMG_HW);
    const float4 rfB = *(const float4*)(img + baseB);
    const float4 gfB = *(const float4*)(img + baseB + IMG_HW);
    const float4 bfB = *(const float4*)(img + baseB + 2 * IMG_HW);

    // quant tables: fs fp64 (pre-rint path), ds f32 (post-rint path)
    if (t < 128) {
        const float* tab = (t < 64) ? ytab : ctab;
        double* qf = (t < 64) ? qYfs : qCfs;
        float*  df = (t < 64) ? dsY : dsC;
        int e = t & 63, u = e >> 3, v = e & 7;
        float tfacf = tab[e] * 0.4f;           // f32, matches reference weak-scalar promotion
        double tf = (double)tfacf;
        qf[v * 10 + u] = (double)CT.scalef[u][v] / tf;
        df[v * 12 + u] = (float)(tf * (double)CT.aof[u][v]);
    }
    __syncthreads();   // ONLY cross-wave sync: publishes tables (img loads in flight)

    // per-lane DCT role (constant across tiles)
    const int g = l >> 3, r = l & 7;
    double* blkd = lYd;  float* blkf = yR;
    const double* qfp = qYfs;  const float* dfp = dsY;
    int sD = 18, sF = 20;
    if (g < 4) {
        const int by = g >> 1, bx = g & 1;
        blkd = lYd + by * 144 + bx * 8;   // 8*18
        blkf = yR  + by * 160 + bx * 8;   // 8*20
    } else {
        blkd = (g == 5) ? crP : cbP;
        blkf = (g == 5) ? crR : cbR;
        qfp = qCfs; dfp = dsC;
        sD = 10; sF = 12;
    }

    auto process_tile = [&](const float4 rf, const float4 gf, const float4 bf,
                            const size_t base) {
        // ---- phase 1: fp64 YCbCr, Y -> wave LDS, 2x2-pooled chroma -> wave LDS
        {
            const double kYR =  (double)0.299f    * 255.0, kYG =  (double)0.587f    * 255.0, kYB =  (double)0.114f    * 255.0;
            const double kbR = -(double)0.168736f * 255.0, kbG = -(double)0.331264f * 255.0, kbB =  (double)0.5f      * 255.0;
            const double krR =  (double)0.5f      * 255.0, krG = -(double)0.418688f * 255.0, krB = -(double)0.081312f * 255.0;
            const float rr[4] = {rf.x, rf.y, rf.z, rf.w};
            const float gg[4] = {gf.x, gf.y, gf.z, gf.w};
            const float bb[4] = {bf.x, bf.y, bf.z, bf.w};
            double Yv[4];
            double cb0 = 0.0, cb1 = 0.0, cr0 = 0.0, cr1 = 0.0;
            #pragma unroll
            for (int i = 0; i < 4; i++) {
                double R = (double)rr[i], G = (double)gg[i], B = (double)bb[i];
                Yv[i] = kYR * R + kYG * G + kYB * B;
                double Cb = kbR * R + kbG * G + kbB * B + 128.0;
                double Cr = krR * R + krG * G + krB * B + 128.0;
                if (i < 2) { cb0 += Cb; cr0 += Cr; } else { cb1 += Cb; cr1 += Cr; }
            }
            double2* yw = (double2*)(lYd + row * 18 + q * 4);
            yw[0] = make_double2(Yv[0], Yv[1]);
            yw[1] = make_double2(Yv[2], Yv[3]);
            // vertical pool with row-partner lane (row^1 == lane^4)
            cb0 += __shfl_xor(cb0, 4);
            cb1 += __shfl_xor(cb1, 4);
            cr0 += __shfl_xor(cr0, 4);
            cr1 += __shfl_xor(cr1, 4);
            if ((row & 1) == 0) {
                const int pr = row >> 1;
                *(double2*)(cbP + pr * 10 + q * 2) = make_double2(cb0 * 0.25, cb1 * 0.25);
                *(double2*)(crP + pr * 10 + q * 2) = make_double2(cr0 * 0.25, cr1 * 0.25);
            }
        }
        asm volatile("s_waitcnt lgkmcnt(0)" ::: "memory");   // phase-1 writes visible (wave-local)

        // ---- DCT pipeline: 6 blocks (4 Y + cb + cr) x 8 lanes; lanes 48..63 idle
        if (g < 6) {
            // stage A: row pass (fp64). -128 shift only affects v=0.
            const double* sp = blkd + r * sD;
            const double2 a01 = *(const double2*)(sp + 0);
            const double2 a23 = *(const double2*)(sp + 2);
            const double2 a45 = *(const double2*)(sp + 4);
            const double2 a67 = *(const double2*)(sp + 6);
            const double a[8] = {a01.x, a01.y, a23.x, a23.y, a45.x, a45.y, a67.x, a67.y};
            double s1[8];
            fwd8_d(a, s1);
            s1[0] -= 1024.0;   // 8 * 128

            // T1: in-place transpose (own block region; WAR safe: in-order DS per wave)
            #pragma unroll
            for (int v = 0; v < 8; v++) blkd[v * sD + r] = s1[v];
            asm volatile("s_waitcnt lgkmcnt(0)" ::: "memory");
            const double* rp = blkd + r * sD;
            const double2 b01 = *(const double2*)(rp + 0);
            const double2 b23 = *(const double2*)(rp + 2);
            const double2 b45 = *(const double2*)(rp + 4);
            const double2 b67 = *(const double2*)(rp + 6);
            const double s2[8] = {b01.x, b01.y, b23.x, b23.y, b45.x, b45.y, b67.x, b67.y};

            // stage B: column pass (fp64) + quant + diff_round + dequant
            double D[8];
            fwd8_d(s2, D);
            const double2 f01 = *(const double2*)(qfp + r * 10 + 0);
            const double2 f23 = *(const double2*)(qfp + r * 10 + 2);
            const double2 f45 = *(const double2*)(qfp + r * 10 + 4);
            const double2 f67 = *(const double2*)(qfp + r * 10 + 6);
            const double fsv[8] = {f01.x, f01.y, f23.x, f23.y, f45.x, f45.y, f67.x, f67.y};
            const float4 dA = *(const float4*)(dfp + r * 12);
            const float4 dB = *(const float4*)(dfp + r * 12 + 4);
            const float dsv[8] = {dA.x, dA.y, dA.z, dA.w, dB.x, dB.y, dB.z, dB.w};
            float dq[8];
            #pragma unroll
            for (int u = 0; u < 8; u++) {
                double xq = D[u] * fsv[u];
                double rq = rint(xq);
                float ef  = (float)(xq - rq);        // exact boundary decision stays fp64
                float rqf = (float)rq;
                dq[u] = (rqf + ef * ef * ef) * dsv[u];
            }

            // stage C: IDCT over u (fp32); lane r holds column v=r
            float mc[8];
            inv8_f(dq, mc);

            // T2: in-place f32 transpose in overlay region (aliases fp64; safe: all fp64
            // reads retired via the register dependency chain feeding mc)
            #pragma unroll
            for (int p = 0; p < 8; p++) blkf[p * sF + r] = mc[p];
            asm volatile("s_waitcnt lgkmcnt(0)" ::: "memory");
            const float* fp_ = blkf + r * sF;
            const float4 m0 = *(const float4*)(fp_);
            const float4 m1 = *(const float4*)(fp_ + 4);
            const float mrow[8] = {m0.x, m0.y, m0.z, m0.w, m1.x, m1.y, m1.z, m1.w};

            // stage D: IDCT over v (fp32), write spatial row r
            float px[8];
            inv8_f(mrow, px);
            float* fw = blkf + r * sF;
            *(float4*)(fw)     = make_float4(fmaf(0.25f, px[0], 128.0f), fmaf(0.25f, px[1], 128.0f),
                                             fmaf(0.25f, px[2], 128.0f), fmaf(0.25f, px[3], 128.0f));
            *(float4*)(fw + 4) = make_float4(fmaf(0.25f, px[4], 128.0f), fmaf(0.25f, px[5], 128.0f),
                                             fmaf(0.25f, px[6], 128.0f), fmaf(0.25f, px[7], 128.0f));
        }
        asm volatile("s_waitcnt lgkmcnt(0)" ::: "memory");   // stage-D writes visible (wave-local)

        // ---- phase 3: upsample chroma, YCbCr->RGB, clip, /255, cached float4 stores
        {
            const float4 yv  = *(const float4*)(yR + row * 20 + q * 4);
            const float2 cbv = *(const float2*)(cbR + (row >> 1) * 12 + q * 2);
            const float2 crv = *(const float2*)(crR + (row >> 1) * 12 + q * 2);
            const float yy[4]  = {yv.x, yv.y, yv.z, yv.w};
            const float cbs[2] = {cbv.x - 128.0f, cbv.y - 128.0f};
            const float crs[2] = {crv.x - 128.0f, crv.y - 128.0f};
            float R4[4], G4[4], B4[4];
            #pragma unroll
            for (int i = 0; i < 4; i++) {
                float Yv = yy[i], Cb = cbs[i >> 1], Cr = crs[i >> 1];
                float Rr = Yv + 1.402f * Cr;
                float Gg = Yv - 0.344136f * Cb - 0.714136f * Cr;
                float Bb = Yv + 1.772f * Cb;
                R4[i] = fminf(fmaxf(Rr, 0.0f), 255.0f) * (1.0f / 255.0f);
                G4[i] = fminf(fmaxf(Gg, 0.0f), 255.0f) * (1.0f / 255.0f);
                B4[i] = fminf(fmaxf(Bb, 0.0f), 255.0f) * (1.0f / 255.0f);
            }
            *(float4*)(out + base)              = make_float4(R4[0], R4[1], R4[2], R4[3]);
            *(float4*)(out + base + IMG_HW)     = make_float4(G4[0], G4[1], G4[2], G4[3]);
            *(float4*)(out + base + 2 * IMG_HW) = make_float4(B4[0], B4[1], B4[2], B4[3]);
        }
        // no barrier: next tile's phase-1 DS writes cannot pass this tile's DS reads
        // (DS ops retire in issue order within a wave)
    };

    process_tile(rfA, gfA, bfA, baseA);
    process_tile(rfB, gfB, bfB, baseB);
}

extern "C" void kernel_launch(void* const* d_in, const int* in_sizes, int n_in,
                              void* d_out, int out_size, void* d_ws, size_t ws_size,
                              hipStream_t stream) {
    (void)n_in; (void)out_size; (void)d_ws; (void)ws_size;
    const float* img = (const float*)d_in[0];
    const float* yt  = (const float*)d_in[1];
    const float* ct  = (const float*)d_in[2];
    float* out = (float*)d_out;
    int B = in_sizes[0] / (3 * IMG_HW);    // 32
    dim3 grid(IMG_W / 128, IMG_H / 16, B); // (4, 32, 32)
    djpeg_kernel<<<grid, dim3(256, 1, 1), 0, stream>>>(img, yt, ct, out);
}

// Round 6
// 197.980 us; speedup vs baseline: 1.0271x; 1.0271x over previous
//
#include <hip/hip_runtime.h>
#include <math.h>

#define IMG_H 512
#define IMG_W 512
#define IMG_HW (IMG_H * IMG_W)

namespace {

// float32-rounded cos(k*pi/16) values
constexpr float CFv[9] = {
    1.0f,
    0.98078528040323044913f,
    0.92387953251128675613f,
    0.83146961230254523708f,
    0.70710678118654752440f,
    0.55557023301960222474f,
    0.38268343236508977173f,
    0.19509032201612826785f,
    0.0f
};

struct CTab {
    float  cf[8][8];     // C[x][u] = f32(cos((2x+1)u pi/16))
    double cd[8][8];     // promoted to double
    float  aof[8][8];    // ALPHA outer product (f32)
    float  scalef[8][8]; // DCT_SCALE = ALPHA*0.25
};

constexpr CTab make_ctab() {
    CTab t{};
    for (int y = 0; y < 8; y++) {
        for (int v = 0; v < 8; v++) {
            int a = ((2 * y + 1) * v) & 31;
            if (a > 16) a = 32 - a;
            float val = (a <= 8) ? CFv[a] : -CFv[16 - a];
            t.cf[y][v] = val;
            t.cd[y][v] = (double)val;
        }
    }
    constexpr float A0 = 0.70710678118654752440f;
    for (int u = 0; u < 8; u++) {
        for (int v = 0; v < 8; v++) {
            float au = (u == 0) ? A0 : 1.0f;
            float av = (v == 0) ? A0 : 1.0f;
            float ao = au * av;
            t.aof[u][v] = ao;
            t.scalef[u][v] = ao * 0.25f;
        }
    }
    return t;
}

constexpr CTab CT = make_ctab();

// forward 8-pt pass (fp64), even/odd butterfly: s[v] = sum_y a[y]*cd[y][v]
__device__ __forceinline__ void fwd8_d(const double a[8], double s[8]) {
    double e0 = a[0] + a[7], e1 = a[1] + a[6], e2 = a[2] + a[5], e3 = a[3] + a[4];
    double o0 = a[0] - a[7], o1 = a[1] - a[6], o2 = a[2] - a[5], o3 = a[3] - a[4];
    double ee0 = e0 + e3, ee1 = e1 + e2, eo0 = e0 - e3, eo1 = e1 - e2;
    s[0] = ee0 + ee1;
    s[4] = (ee0 - ee1) * CT.cd[0][4];
    s[2] = eo0 * CT.cd[0][2] + eo1 * CT.cd[1][2];
    s[6] = eo0 * CT.cd[0][6] + eo1 * CT.cd[1][6];
    #pragma unroll
    for (int k = 0; k < 4; k++) {
        const int v = 2 * k + 1;
        s[v] = o0 * CT.cd[0][v] + o1 * CT.cd[1][v] + o2 * CT.cd[2][v] + o3 * CT.cd[3][v];
    }
}

// inverse 8-pt pass (fp32), output-symmetry butterfly: m[x] = sum_u d[u]*cf[x][u]
__device__ __forceinline__ void inv8_f(const float d[8], float m[8]) {
    float eea = fmaf(CT.cf[0][4], d[4], d[0]);
    float eeb = fmaf(CT.cf[1][4], d[4], d[0]);
    float u2a = d[2] * CT.cf[0][2] + d[6] * CT.cf[0][6];
    float u2b = d[2] * CT.cf[1][2] + d[6] * CT.cf[1][6];
    float E0 = eea + u2a, E1 = eeb + u2b, E2 = eeb - u2b, E3 = eea - u2a;
    float O0 = d[1] * CT.cf[0][1] + d[3] * CT.cf[0][3] + d[5] * CT.cf[0][5] + d[7] * CT.cf[0][7];
    float O1 = d[1] * CT.cf[1][1] + d[3] * CT.cf[1][3] + d[5] * CT.cf[1][5] + d[7] * CT.cf[1][7];
    float O2 = d[1] * CT.cf[2][1] + d[3] * CT.cf[2][3] + d[5] * CT.cf[2][5] + d[7] * CT.cf[2][7];
    float O3 = d[1] * CT.cf[3][1] + d[3] * CT.cf[3][3] + d[5] * CT.cf[3][5] + d[7] * CT.cf[3][7];
    m[0] = E0 + O0; m[7] = E0 - O0;
    m[1] = E1 + O1; m[6] = E1 - O1;
    m[2] = E2 + O2; m[5] = E2 - O2;
    m[3] = E3 + O3; m[4] = E3 - O3;
}

// in-register 8x8 transpose across the 8-lane group (proven bit-exact in R0)
__device__ __forceinline__ void xpose8_d(double v[8]) {
    const int l = threadIdx.x & 7;
    #pragma unroll
    for (int m = 1; m < 8; m <<= 1) {
        #pragma unroll
        for (int k = 0; k < 8; k++) {
            if ((k & m) == 0) {
                const int kp = k | m;
                double send = (l & m) ? v[k] : v[kp];
                double recv = __shfl_xor(send, m);
                v[k]  = (l & m) ? recv : v[k];
                v[kp] = (l & m) ? v[kp] : recv;
            }
        }
    }
}

__device__ __forceinline__ void xpose8_f(float v[8]) {
    const int l = threadIdx.x & 7;
    #pragma unroll
    for (int m = 1; m < 8; m <<= 1) {
        #pragma unroll
        for (int k = 0; k < 8; k++) {
            if ((k & m) == 0) {
                const int kp = k | m;
                float send = (l & m) ? v[k] : v[kp];
                float recv = __shfl_xor(send, m);
                v[k]  = (l & m) ? recv : v[k];
                v[kp] = (l & m) ? v[kp] : recv;
            }
        }
    }
}

} // namespace

// ---- LDS: quant tables only (shared, 2 KB) ---------------------------------
#define OFF_QYF 0
#define OFF_QCF 640
#define OFF_DSY 1280
#define OFF_DSC 1664
#define SMEM_BYTES 2048

// Lane map per wave (one 16x16 pixel tile per wave):
//   l = 8*g + r.  g 0-3: Y blocks (2x2 of 8x8), lane holds pixel row
//   pr=(g>>1)*8+r, cols (g&1)*8 .. +8.  g=4: Cb block, g=5: Cr block
//   (inputs arrive via shuffle from Y lanes).  g 6,7: idle.
__global__ void __launch_bounds__(256, 8) djpeg_kernel(
    const float* __restrict__ img,
    const float* __restrict__ ytab,
    const float* __restrict__ ctab,
    float* __restrict__ out)
{
    __shared__ __align__(16) unsigned char smem[SMEM_BYTES];
    double* qYfs = (double*)(smem + OFF_QYF);
    double* qCfs = (double*)(smem + OFF_QCF);
    float*  dsY  = (float*)(smem + OFF_DSY);
    float*  dsC  = (float*)(smem + OFF_DSC);

    const int t = threadIdx.x;
    const int w = t >> 6, l = t & 63;
    const int g = l >> 3, r = l & 7;

    const int bi = blockIdx.z;
    const int X0 = blockIdx.x * 64 + w * 16;   // wave-private 16x16 tile
    const int Y0 = blockIdx.y * 16;

    // Y-lane pixel coordinates: 8 contiguous pixels = this lane's DCT row
    const int pr = (g >> 1) * 8 + r;
    const int pc = (g & 1) * 8;
    const size_t pbase = ((size_t)bi * 3) * IMG_HW + (size_t)(Y0 + pr) * IMG_W + X0 + pc;

    // issue the 6 vector loads up front (Y lanes only; address valid only there)
    float4 rf0, rf1, gf0, gf1, bf0, bf1;
    if (l < 32) {
        rf0 = *(const float4*)(img + pbase);
        rf1 = *(const float4*)(img + pbase + 4);
        gf0 = *(const float4*)(img + pbase + IMG_HW);
        gf1 = *(const float4*)(img + pbase + IMG_HW + 4);
        bf0 = *(const float4*)(img + pbase + 2 * IMG_HW);
        bf1 = *(const float4*)(img + pbase + 2 * IMG_HW + 4);
    }

    // quant tables: fs fp64 (pre-rint path), ds f32 (post-rint path)
    if (t < 128) {
        const float* tab = (t < 64) ? ytab : ctab;
        double* qf = (t < 64) ? qYfs : qCfs;
        float*  df = (t < 64) ? dsY : dsC;
        int e = t & 63, u = e >> 3, v = e & 7;
        float tfacf = tab[e] * 0.4f;           // f32, matches reference weak-scalar promotion
        double tf = (double)tfacf;
        qf[v * 10 + u] = (double)CT.scalef[u][v] / tf;
        df[v * 12 + u] = (float)(tf * (double)CT.aof[u][v]);
    }
    __syncthreads();   // only cross-wave sync: publishes tables (img loads in flight)

    // ---- phase 1 (Y lanes): fp64 YCbCr for own 8 px; 2x2 pool of chroma
    double a[8]  = {0.0, 0.0, 0.0, 0.0, 0.0, 0.0, 0.0, 0.0};
    double vb[4] = {0.0, 0.0, 0.0, 0.0};
    double vr[4] = {0.0, 0.0, 0.0, 0.0};
    if (l < 32) {
        const double kYR =  (double)0.299f    * 255.0, kYG =  (double)0.587f    * 255.0, kYB =  (double)0.114f    * 255.0;
        const double kbR = -(double)0.168736f * 255.0, kbG = -(double)0.331264f * 255.0, kbB =  (double)0.5f      * 255.0;
        const double krR =  (double)0.5f      * 255.0, krG = -(double)0.418688f * 255.0, krB = -(double)0.081312f * 255.0;
        const float rr_[8] = {rf0.x, rf0.y, rf0.z, rf0.w, rf1.x, rf1.y, rf1.z, rf1.w};
        const float gg_[8] = {gf0.x, gf0.y, gf0.z, gf0.w, gf1.x, gf1.y, gf1.z, gf1.w};
        const float bb_[8] = {bf0.x, bf0.y, bf0.z, bf0.w, bf1.x, bf1.y, bf1.z, bf1.w};
        #pragma unroll
        for (int k = 0; k < 4; k++) {
            double cbp = 0.0, crp = 0.0;
            #pragma unroll
            for (int h = 0; h < 2; h++) {
                const int j = 2 * k + h;
                double R = (double)rr_[j], G = (double)gg_[j], B = (double)bb_[j];
                a[j] = kYR * R + kYG * G + kYB * B;
                double Cb = kbR * R + kbG * G + kbB * B + 128.0;
                double Cr = krR * R + krG * G + krB * B + 128.0;
                cbp += Cb;
                crp += Cr;
            }
            // vertical pool with row partner (pr^1 == lane^1), *0.25
            vb[k] = (cbp + __shfl_xor(cbp, 1)) * 0.25;
            vr[k] = (crp + __shfl_xor(crp, 1)) * 0.25;
        }
    }

    // ---- gather pooled chroma rows into cb/cr DCT lanes (uniform shuffles)
    {
        const int rr2  = (l - 32) & 7;                       // chroma lane's block row
        const int srcA = ((rr2 >> 2) * 16) + 2 * (rr2 & 3);  // Y lane holding cols 0-3
        const int srcB = srcA + 8;                           // cols 4-7
        double ga[8];
        #pragma unroll
        for (int k = 0; k < 4; k++) {
            double bA = __shfl(vb[k], srcA);
            double bB = __shfl(vb[k], srcB);
            double rA = __shfl(vr[k], srcA);
            double rB = __shfl(vr[k], srcB);
            const bool isCr = (l >= 40);
            ga[k]     = isCr ? rA : bA;
            ga[4 + k] = isCr ? rB : bB;
        }
        if (g >= 4) {
            #pragma unroll
            for (int k = 0; k < 8; k++) a[k] = ga[k];
        }
    }

    // ---- DCT pipeline, fully in-register (6 active 8-lane groups)
    double s1[8];
    fwd8_d(a, s1);
    s1[0] -= 1024.0;          // -128 shift only affects v=0 (sum C[y][v>0] = 0)
    xpose8_d(s1);             // lane r now holds column v=r
    double D[8];
    fwd8_d(s1, D);

    const double* qfp = (g < 4) ? qYfs : qCfs;
    const float*  dfp = (g < 4) ? dsY : dsC;
    const double2 f01 = *(const double2*)(qfp + r * 10 + 0);
    const double2 f23 = *(const double2*)(qfp + r * 10 + 2);
    const double2 f45 = *(const double2*)(qfp + r * 10 + 4);
    const double2 f67 = *(const double2*)(qfp + r * 10 + 6);
    const double fsv[8] = {f01.x, f01.y, f23.x, f23.y, f45.x, f45.y, f67.x, f67.y};
    const float4 dA = *(const float4*)(dfp + r * 12);
    const float4 dB = *(const float4*)(dfp + r * 12 + 4);
    const float dsv[8] = {dA.x, dA.y, dA.z, dA.w, dB.x, dB.y, dB.z, dB.w};
    float dq[8];
    #pragma unroll
    for (int u = 0; u < 8; u++) {
        double xq = D[u] * fsv[u];
        double rq = rint(xq);
        float ef  = (float)(xq - rq);        // exact boundary decision stays fp64
        float rqf = (float)rq;
        dq[u] = (rqf + ef * ef * ef) * dsv[u];
    }

    float mc[8];
    inv8_f(dq, mc);           // lane r = column v=r, mc[x] over rows
    xpose8_f(mc);             // lane r now holds spatial row r over v
    float px[8];
    inv8_f(mc, px);           // spatial row r, cols 0-7
    #pragma unroll
    for (int j = 0; j < 8; j++) px[j] = fmaf(0.25f, px[j], 128.0f);

    // ---- upsample chroma back to Y lanes (uniform shuffles), RGB, store
    {
        const int rrY = (g >> 1) * 4 + (r >> 1);   // pooled row for this Y lane
        const int sCb = 32 + rrY, sCr = 40 + rrY;
        float cbU[4], crU[4];
        #pragma unroll
        for (int k = 0; k < 4; k++) {
            float lo = __shfl(px[k], sCb);
            float hi = __shfl(px[4 + k], sCb);
            cbU[k] = (g & 1) ? hi : lo;
            lo = __shfl(px[k], sCr);
            hi = __shfl(px[4 + k], sCr);
            crU[k] = (g & 1) ? hi : lo;
        }
        if (l < 32) {
            float R8[8], G8[8], B8[8];
            #pragma unroll
            for (int j = 0; j < 8; j++) {
                float Yv = px[j];
                float Cb = cbU[j >> 1] - 128.0f;
                float Cr = crU[j >> 1] - 128.0f;
                float Rr = Yv + 1.402f * Cr;
                float Gg = Yv - 0.344136f * Cb - 0.714136f * Cr;
                float Bb = Yv + 1.772f * Cb;
                R8[j] = fminf(fmaxf(Rr, 0.0f), 255.0f) * (1.0f / 255.0f);
                G8[j] = fminf(fmaxf(Gg, 0.0f), 255.0f) * (1.0f / 255.0f);
                B8[j] = fminf(fmaxf(Bb, 0.0f), 255.0f) * (1.0f / 255.0f);
            }
            float* o0 = out + pbase;
            float* o1 = out + pbase + IMG_HW;
            float* o2 = out + pbase + 2 * IMG_HW;
            *(float4*)(o0)     = make_float4(R8[0], R8[1], R8[2], R8[3]);
            *(float4*)(o0 + 4) = make_float4(R8[4], R8[5], R8[6], R8[7]);
            *(float4*)(o1)     = make_float4(G8[0], G8[1], G8[2], G8[3]);
            *(float4*)(o1 + 4) = make_float4(G8[4], G8[5], G8[6], G8[7]);
            *(float4*)(o2)     = make_float4(B8[0], B8[1], B8[2], B8[3]);
            *(float4*)(o2 + 4) = make_float4(B8[4], B8[5], B8[6], B8[7]);
        }
    }
}

extern "C" void kernel_launch(void* const* d_in, const int* in_sizes, int n_in,
                              void* d_out, int out_size, void* d_ws, size_t ws_size,
                              hipStream_t stream) {
    (void)n_in; (void)out_size; (void)d_ws; (void)ws_size;
    const float* img = (const float*)d_in[0];
    const float* yt  = (const float*)d_in[1];
    const float* ct  = (const float*)d_in[2];
    float* out = (float*)d_out;
    int B = in_sizes[0] / (3 * IMG_HW);   // 32
    dim3 grid(IMG_W / 64, IMG_H / 16, B); // (8, 32, 32)
    djpeg_kernel<<<grid, dim3(256, 1, 1), 0, stream>>>(img, yt, ct, out);
}

// Round 7
// 181.661 us; speedup vs baseline: 1.1193x; 1.0898x over previous
//
#include <hip/hip_runtime.h>
#include <math.h>

#define IMG_H 512
#define IMG_W 512
#define IMG_HW (IMG_H * IMG_W)

namespace {

// float32-rounded cos(k*pi/16) values
constexpr float CFv[9] = {
    1.0f,
    0.98078528040323044913f,
    0.92387953251128675613f,
    0.83146961230254523708f,
    0.70710678118654752440f,
    0.55557023301960222474f,
    0.38268343236508977173f,
    0.19509032201612826785f,
    0.0f
};

struct CTab {
    float  cf[8][8];     // C[x][u] = f32(cos((2x+1)u pi/16))
    double cd[8][8];     // promoted to double
    float  aof[8][8];    // ALPHA outer product (f32)
    float  scalef[8][8]; // DCT_SCALE = ALPHA*0.25
};

constexpr CTab make_ctab() {
    CTab t{};
    for (int y = 0; y < 8; y++) {
        for (int v = 0; v < 8; v++) {
            int a = ((2 * y + 1) * v) & 31;
            if (a > 16) a = 32 - a;
            float val = (a <= 8) ? CFv[a] : -CFv[16 - a];
            t.cf[y][v] = val;
            t.cd[y][v] = (double)val;
        }
    }
    constexpr float A0 = 0.70710678118654752440f;
    for (int u = 0; u < 8; u++) {
        for (int v = 0; v < 8; v++) {
            float au = (u == 0) ? A0 : 1.0f;
            float av = (v == 0) ? A0 : 1.0f;
            float ao = au * av;
            t.aof[u][v] = ao;
            t.scalef[u][v] = ao * 0.25f;
        }
    }
    return t;
}

constexpr CTab CT = make_ctab();

// forward 8-pt pass (fp64), even/odd butterfly: s[v] = sum_y a[y]*cd[y][v]
__device__ __forceinline__ void fwd8_d(const double a[8], double s[8]) {
    double e0 = a[0] + a[7], e1 = a[1] + a[6], e2 = a[2] + a[5], e3 = a[3] + a[4];
    double o0 = a[0] - a[7], o1 = a[1] - a[6], o2 = a[2] - a[5], o3 = a[3] - a[4];
    double ee0 = e0 + e3, ee1 = e1 + e2, eo0 = e0 - e3, eo1 = e1 - e2;
    s[0] = ee0 + ee1;
    s[4] = (ee0 - ee1) * CT.cd[0][4];
    s[2] = eo0 * CT.cd[0][2] + eo1 * CT.cd[1][2];
    s[6] = eo0 * CT.cd[0][6] + eo1 * CT.cd[1][6];
    #pragma unroll
    for (int k = 0; k < 4; k++) {
        const int v = 2 * k + 1;
        s[v] = o0 * CT.cd[0][v] + o1 * CT.cd[1][v] + o2 * CT.cd[2][v] + o3 * CT.cd[3][v];
    }
}

// inverse 8-pt pass (fp32), output-symmetry butterfly: m[x] = sum_u d[u]*cf[x][u]
__device__ __forceinline__ void inv8_f(const float d[8], float m[8]) {
    float eea = fmaf(CT.cf[0][4], d[4], d[0]);
    float eeb = fmaf(CT.cf[1][4], d[4], d[0]);
    float u2a = d[2] * CT.cf[0][2] + d[6] * CT.cf[0][6];
    float u2b = d[2] * CT.cf[1][2] + d[6] * CT.cf[1][6];
    float E0 = eea + u2a, E1 = eeb + u2b, E2 = eeb - u2b, E3 = eea - u2a;
    float O0 = d[1] * CT.cf[0][1] + d[3] * CT.cf[0][3] + d[5] * CT.cf[0][5] + d[7] * CT.cf[0][7];
    float O1 = d[1] * CT.cf[1][1] + d[3] * CT.cf[1][3] + d[5] * CT.cf[1][5] + d[7] * CT.cf[1][7];
    float O2 = d[1] * CT.cf[2][1] + d[3] * CT.cf[2][3] + d[5] * CT.cf[2][5] + d[7] * CT.cf[2][7];
    float O3 = d[1] * CT.cf[3][1] + d[3] * CT.cf[3][3] + d[5] * CT.cf[3][5] + d[7] * CT.cf[3][7];
    m[0] = E0 + O0; m[7] = E0 - O0;
    m[1] = E1 + O1; m[6] = E1 - O1;
    m[2] = E2 + O2; m[5] = E2 - O2;
    m[3] = E3 + O3; m[4] = E3 - O3;
}

} // namespace

// ---- LDS layout (bytes) ----------------------------------------------------
// TWO strip regions (strip s at smem + s*12800), each identical to R1's layout:
//   lY    double[16][66] @0     8448  (f32 overlays after B2: yR stride 68 @0,
//                                      cbR stride 36 @4352, crR stride 36 @5504)
//   cbP   double[8][34]  @8448  2176
//   crP   double[8][34]  @10624 2176
// Shared quant tables:
//   qYfs double[8][10] @25600 ; qCfs @26240 ; dsY f32[8][12] @26880 ; dsC @27264
#define STRIP_BYTES 12800
#define OFF_CBP 8448
#define OFF_CRP 10624
#define OFF_CBR 4352
#define OFF_CRR 5504
#define OFF_QYF 25600
#define OFF_QCF 26240
#define OFF_DSY 26880
#define OFF_DSC 27264
#define SMEM_BYTES 27648

__global__ void __launch_bounds__(256, 5) djpeg_kernel(
    const float* __restrict__ img,
    const float* __restrict__ ytab,
    const float* __restrict__ ctab,
    float* __restrict__ out)
{
    __shared__ __align__(16) unsigned char smem[SMEM_BYTES];
    double* lY0  = (double*)(smem);
    double* cbP0 = (double*)(smem + OFF_CBP);
    double* crP0 = (double*)(smem + OFF_CRP);
    float*  yR0  = (float*)(smem);
    float*  cbR0 = (float*)(smem + OFF_CBR);
    float*  crR0 = (float*)(smem + OFF_CRR);
    double* lY1  = (double*)(smem + STRIP_BYTES);
    double* cbP1 = (double*)(smem + STRIP_BYTES + OFF_CBP);
    double* crP1 = (double*)(smem + STRIP_BYTES + OFF_CRP);
    float*  yR1  = (float*)(smem + STRIP_BYTES);
    float*  cbR1 = (float*)(smem + STRIP_BYTES + OFF_CBR);
    float*  crR1 = (float*)(smem + STRIP_BYTES + OFF_CRR);
    double* qYfs = (double*)(smem + OFF_QYF);
    double* qCfs = (double*)(smem + OFF_QCF);
    float*  dsY  = (float*)(smem + OFF_DSY);
    float*  dsC  = (float*)(smem + OFF_DSC);

    const int t  = threadIdx.x;
    const int X0 = blockIdx.x * 64;
    const int Y0 = blockIdx.y * 32;       // two strips: Y0, Y0+16
    const int bi = blockIdx.z;
    const int xq = t & 15, yb = t >> 4;   // thread = (row yb 0..15, col quad xq)

    // ---- issue BOTH strips' global loads up front (6 KB/wave in flight)
    const size_t base0 = ((size_t)bi * 3) * IMG_HW + (size_t)(Y0 + yb) * IMG_W + X0 + xq * 4;
    const size_t base1 = base0 + (size_t)16 * IMG_W;
    const float4 rf0 = *(const float4*)(img + base0);
    const float4 gf0 = *(const float4*)(img + base0 + IMG_HW);
    const float4 bf0 = *(const float4*)(img + base0 + 2 * IMG_HW);
    const float4 rf1 = *(const float4*)(img + base1);
    const float4 gf1 = *(const float4*)(img + base1 + IMG_HW);
    const float4 bf1 = *(const float4*)(img + base1 + 2 * IMG_HW);

    // ---- quant tables: fs fp64 (pre-rint path), ds f32 (post-rint path)
    if (t < 128) {
        const float* tab = (t < 64) ? ytab : ctab;
        double* qf = (t < 64) ? qYfs : qCfs;
        float*  df = (t < 64) ? dsY : dsC;
        int e = t & 63, u = e >> 3, v = e & 7;
        float tfacf = tab[e] * 0.4f;           // f32, matches reference weak-scalar promotion
        double tf = (double)tfacf;
        qf[v * 10 + u] = (double)CT.scalef[u][v] / tf;
        df[v * 12 + u] = (float)(tf * (double)CT.aof[u][v]);
    }

    // ---- phase 1 (both strips): fp64 YCbCr, Y -> LDS, 2x2-pooled chroma -> LDS
    auto phase1 = [&](const float4 rf, const float4 gf, const float4 bf,
                      double* lY, double* cbP, double* crP) {
        const double kYR =  (double)0.299f    * 255.0, kYG =  (double)0.587f    * 255.0, kYB =  (double)0.114f    * 255.0;
        const double kbR = -(double)0.168736f * 255.0, kbG = -(double)0.331264f * 255.0, kbB =  (double)0.5f      * 255.0;
        const double krR =  (double)0.5f      * 255.0, krG = -(double)0.418688f * 255.0, krB = -(double)0.081312f * 255.0;
        const float rr[4] = {rf.x, rf.y, rf.z, rf.w};
        const float gg[4] = {gf.x, gf.y, gf.z, gf.w};
        const float bb[4] = {bf.x, bf.y, bf.z, bf.w};
        double Yv[4];
        double cb0 = 0.0, cb1 = 0.0, cr0 = 0.0, cr1 = 0.0;
        #pragma unroll
        for (int i = 0; i < 4; i++) {
            double R = (double)rr[i], G = (double)gg[i], B = (double)bb[i];
            Yv[i] = kYR * R + kYG * G + kYB * B;
            double Cb = kbR * R + kbG * G + kbB * B + 128.0;
            double Cr = krR * R + krG * G + krB * B + 128.0;
            if (i < 2) { cb0 += Cb; cr0 += Cr; } else { cb1 += Cb; cr1 += Cr; }
        }
        double2* yw = (double2*)(lY + yb * 66 + xq * 4);
        yw[0] = make_double2(Yv[0], Yv[1]);
        yw[1] = make_double2(Yv[2], Yv[3]);
        // vertical pool with row-partner lane (yb^1 == lane^16, same wave)
        cb0 += __shfl_xor(cb0, 16);
        cb1 += __shfl_xor(cb1, 16);
        cr0 += __shfl_xor(cr0, 16);
        cr1 += __shfl_xor(cr1, 16);
        if ((yb & 1) == 0) {
            const int pr = yb >> 1;
            *(double2*)(cbP + pr * 34 + xq * 2) = make_double2(cb0 * 0.25, cb1 * 0.25);
            *(double2*)(crP + pr * 34 + xq * 2) = make_double2(cr0 * 0.25, cr1 * 0.25);
        }
    };
    phase1(rf0, gf0, bf0, lY0, cbP0, crP0);
    phase1(rf1, gf1, bf1, lY1, cbP1, crP1);
    __syncthreads();  // B1 (also publishes quant tables)

    // ---- per-lane DCT role (same for both strips): 24 blocks x 8 lanes, t<192
    const bool act = (t < 192);
    const int r = t & 7;
    int eD = 0, eF = 0, sD = 66, sF = 68;
    const double* qfp = qYfs;  const float* dfp = dsY;
    if (t < 128) {                        // 16 Y blocks per strip
        int g = t >> 3, by = g >> 3, bx = g & 7;
        eD = (by * 8) * 66 + bx * 8;
        eF = (by * 8) * 68 + bx * 8;
    } else {                              // 4 cb + 4 cr blocks per strip
        int c = t - 128, isCr = c >> 5, g2 = (c >> 3) & 3;
        eD = (isCr ? (OFF_CRP / 8) : (OFF_CBP / 8)) + g2 * 8;
        eF = (isCr ? (OFF_CRR / 4) : (OFF_CBR / 4)) + g2 * 8;
        qfp = qCfs; dfp = dsC;
        sD = 34; sF = 36;
    }
    double* bdA = lY0 + eD;  double* bdB = lY1 + eD;
    float*  bfA = yR0 + eF;  float*  bfB = yR1 + eF;

    float dqA[8], dqB[8];
    if (act) {
        // stage A, strip 0: row pass (fp64) + T1 column writes
        {
            const double* sp = bdA + r * sD;
            const double2 a01 = *(const double2*)(sp + 0);
            const double2 a23 = *(const double2*)(sp + 2);
            const double2 a45 = *(const double2*)(sp + 4);
            const double2 a67 = *(const double2*)(sp + 6);
            const double a[8] = {a01.x, a01.y, a23.x, a23.y, a45.x, a45.y, a67.x, a67.y};
            double s1[8];
            fwd8_d(a, s1);
            s1[0] -= 1024.0;   // -128 shift only affects v=0 (sum C[y][v>0] = 0)
            #pragma unroll
            for (int v = 0; v < 8; v++) bdA[v * sD + r] = s1[v];
        }
        // stage A, strip 1
        {
            const double* sp = bdB + r * sD;
            const double2 a01 = *(const double2*)(sp + 0);
            const double2 a23 = *(const double2*)(sp + 2);
            const double2 a45 = *(const double2*)(sp + 4);
            const double2 a67 = *(const double2*)(sp + 6);
            const double a[8] = {a01.x, a01.y, a23.x, a23.y, a45.x, a45.y, a67.x, a67.y};
            double s1[8];
            fwd8_d(a, s1);
            s1[0] -= 1024.0;
            #pragma unroll
            for (int v = 0; v < 8; v++) bdB[v * sD + r] = s1[v];
        }
        // ONE drain for both strips' T1 (in-place WAR safe: DS ops retire in wave order)
        asm volatile("s_waitcnt lgkmcnt(0)" ::: "memory");

        // quant factors loaded once, shared by both strips
        const double2 f01 = *(const double2*)(qfp + r * 10 + 0);
        const double2 f23 = *(const double2*)(qfp + r * 10 + 2);
        const double2 f45 = *(const double2*)(qfp + r * 10 + 4);
        const double2 f67 = *(const double2*)(qfp + r * 10 + 6);
        const double fsv[8] = {f01.x, f01.y, f23.x, f23.y, f45.x, f45.y, f67.x, f67.y};
        const float4 dA4 = *(const float4*)(dfp + r * 12);
        const float4 dB4 = *(const float4*)(dfp + r * 12 + 4);
        const float dsv[8] = {dA4.x, dA4.y, dA4.z, dA4.w, dB4.x, dB4.y, dB4.z, dB4.w};

        // stage B, strip 0: column pass + quant + diff_round + dequant
        {
            const double* rp = bdA + r * sD;
            const double2 b01 = *(const double2*)(rp + 0);
            const double2 b23 = *(const double2*)(rp + 2);
            const double2 b45 = *(const double2*)(rp + 4);
            const double2 b67 = *(const double2*)(rp + 6);
            const double s2[8] = {b01.x, b01.y, b23.x, b23.y, b45.x, b45.y, b67.x, b67.y};
            double D[8];
            fwd8_d(s2, D);
            #pragma unroll
            for (int u = 0; u < 8; u++) {
                double xqv = D[u] * fsv[u];
                double rq = rint(xqv);
                float ef  = (float)(xqv - rq);   // exact boundary decision stays fp64
                float rqf = (float)rq;
                dqA[u] = (rqf + ef * ef * ef) * dsv[u];
            }
        }
        // stage B, strip 1
        {
            const double* rp = bdB + r * sD;
            const double2 b01 = *(const double2*)(rp + 0);
            const double2 b23 = *(const double2*)(rp + 2);
            const double2 b45 = *(const double2*)(rp + 4);
            const double2 b67 = *(const double2*)(rp + 6);
            const double s2[8] = {b01.x, b01.y, b23.x, b23.y, b45.x, b45.y, b67.x, b67.y};
            double D[8];
            fwd8_d(s2, D);
            #pragma unroll
            for (int u = 0; u < 8; u++) {
                double xqv = D[u] * fsv[u];
                double rq = rint(xqv);
                float ef  = (float)(xqv - rq);
                float rqf = (float)rq;
                dqB[u] = (rqf + ef * ef * ef) * dsv[u];
            }
        }
    }

    __syncthreads();  // B2: all fp64 LDS reads done chip-wide; f32 overlays writable

    if (act) {
        // stage C + T2 writes, both strips
        float mcA[8], mcB[8];
        inv8_f(dqA, mcA);
        inv8_f(dqB, mcB);
        #pragma unroll
        for (int p = 0; p < 8; p++) bfA[p * sF + r] = mcA[p];
        #pragma unroll
        for (int p = 0; p < 8; p++) bfB[p * sF + r] = mcB[p];
        asm volatile("s_waitcnt lgkmcnt(0)" ::: "memory");   // ONE drain for both T2s

        // T2 readback + stage D, strip 0
        {
            const float* fp_ = bfA + r * sF;
            const float4 m0 = *(const float4*)(fp_);
            const float4 m1 = *(const float4*)(fp_ + 4);
            const float mrow[8] = {m0.x, m0.y, m0.z, m0.w, m1.x, m1.y, m1.z, m1.w};
            float px[8];
            inv8_f(mrow, px);
            float* fw = bfA + r * sF;
            *(float4*)(fw)     = make_float4(fmaf(0.25f, px[0], 128.0f), fmaf(0.25f, px[1], 128.0f),
                                             fmaf(0.25f, px[2], 128.0f), fmaf(0.25f, px[3], 128.0f));
            *(float4*)(fw + 4) = make_float4(fmaf(0.25f, px[4], 128.0f), fmaf(0.25f, px[5], 128.0f),
                                             fmaf(0.25f, px[6], 128.0f), fmaf(0.25f, px[7], 128.0f));
        }
        // T2 readback + stage D, strip 1
        {
            const float* fp_ = bfB + r * sF;
            const float4 m0 = *(const float4*)(fp_);
            const float4 m1 = *(const float4*)(fp_ + 4);
            const float mrow[8] = {m0.x, m0.y, m0.z, m0.w, m1.x, m1.y, m1.z, m1.w};
            float px[8];
            inv8_f(mrow, px);
            float* fw = bfB + r * sF;
            *(float4*)(fw)     = make_float4(fmaf(0.25f, px[0], 128.0f), fmaf(0.25f, px[1], 128.0f),
                                             fmaf(0.25f, px[2], 128.0f), fmaf(0.25f, px[3], 128.0f));
            *(float4*)(fw + 4) = make_float4(fmaf(0.25f, px[4], 128.0f), fmaf(0.25f, px[5], 128.0f),
                                             fmaf(0.25f, px[6], 128.0f), fmaf(0.25f, px[7], 128.0f));
        }
    }
    __syncthreads();  // B3

    // ---- phase 3 (both strips): upsample chroma, YCbCr->RGB, clip, /255, store
    // Store map: per wave, 4 rows x 256 B contiguous per channel -> full-line writes.
    auto phase3 = [&](const float* yR, const float* cbR, const float* crR,
                      const size_t base) {
        const float4 yv  = *(const float4*)(yR + yb * 68 + xq * 4);
        const float2 cbv = *(const float2*)(cbR + (yb >> 1) * 36 + xq * 2);
        const float2 crv = *(const float2*)(crR + (yb >> 1) * 36 + xq * 2);
        const float yy[4]  = {yv.x, yv.y, yv.z, yv.w};
        const float cbs[2] = {cbv.x - 128.0f, cbv.y - 128.0f};
        const float crs[2] = {crv.x - 128.0f, crv.y - 128.0f};
        float R4[4], G4[4], B4[4];
        #pragma unroll
        for (int i = 0; i < 4; i++) {
            float Yv = yy[i], Cb = cbs[i >> 1], Cr = crs[i >> 1];
            float Rr = Yv + 1.402f * Cr;
            float Gg = Yv - 0.344136f * Cb - 0.714136f * Cr;
            float Bb = Yv + 1.772f * Cb;
            R4[i] = fminf(fmaxf(Rr, 0.0f), 255.0f) * (1.0f / 255.0f);
            G4[i] = fminf(fmaxf(Gg, 0.0f), 255.0f) * (1.0f / 255.0f);
            B4[i] = fminf(fmaxf(Bb, 0.0f), 255.0f) * (1.0f / 255.0f);
        }
        *(float4*)(out + base)              = make_float4(R4[0], R4[1], R4[2], R4[3]);
        *(float4*)(out + base + IMG_HW)     = make_float4(G4[0], G4[1], G4[2], G4[3]);
        *(float4*)(out + base + 2 * IMG_HW) = make_float4(B4[0], B4[1], B4[2], B4[3]);
    };
    phase3(yR0, cbR0, crR0, base0);
    phase3(yR1, cbR1, crR1, base1);
}

extern "C" void kernel_launch(void* const* d_in, const int* in_sizes, int n_in,
                              void* d_out, int out_size, void* d_ws, size_t ws_size,
                              hipStream_t stream) {
    (void)n_in; (void)out_size; (void)d_ws; (void)ws_size;
    const float* img = (const float*)d_in[0];
    const float* yt  = (const float*)d_in[1];
    const float* ct  = (const float*)d_in[2];
    float* out = (float*)d_out;
    int B = in_sizes[0] / (3 * IMG_HW);   // 32
    dim3 grid(IMG_W / 64, IMG_H / 32, B); // (8, 16, 32)
    djpeg_kernel<<<grid, dim3(256, 1, 1), 0, stream>>>(img, yt, ct, out);
}